// Round 5
// baseline (1294.048 us; speedup 1.0000x reference)
//
#include <hip/hip_runtime.h>

#define T_STEPS 1024
#define BATCH   256
#define IND     128
#define HID     256
#define OUTD    64

typedef float  f32x4  __attribute__((ext_vector_type(4)));
typedef __bf16 bf16x8 __attribute__((ext_vector_type(8)));

__device__ __forceinline__ bf16x8 cvt8(float4 a, float4 b){
  bf16x8 v;
  v[0]=(__bf16)a.x; v[1]=(__bf16)a.y; v[2]=(__bf16)a.z; v[3]=(__bf16)a.w;
  v[4]=(__bf16)b.x; v[5]=(__bf16)b.y; v[6]=(__bf16)b.z; v[7]=(__bf16)b.w;
  return v;
}

// pack 4 f32 -> 4 fp8(e4m3) bytes in one dword
__device__ __forceinline__ int pk_fp8x4(float a, float b, float c, float d){
  int r = __builtin_amdgcn_cvt_pk_fp8_f32(a, b, 0, false);
  r     = __builtin_amdgcn_cvt_pk_fp8_f32(c, d, r, true);
  return r;
}

// ---------------------------------------------------------------------------
// Kernel 1: Ux[t,b,h] = sum_k x[t,b,k] * U[h,k]   (bf16 out, M = T*B = 262144)
// ---------------------------------------------------------------------------
__global__ __launch_bounds__(256) void ux_gemm(const float* __restrict__ x,
                                               const float* __restrict__ U,
                                               __bf16* __restrict__ uxz){
  __shared__ bf16x8 Ub[4096];   // 16 nt * 4 c * 64 lanes, 64 KB
  const int tid = threadIdx.x;
  for(int s = tid; s < 4096; s += 256){
    const int l = s & 63, c = (s>>6)&3, nt = s>>8;
    const int n = nt*16 + (l&15), k = c*32 + ((l>>4)<<3);
    const float4* p = (const float4*)(U + n*IND + k);
    Ub[s] = cvt8(p[0], p[1]);
  }
  __syncthreads();
  const int wave = tid>>6, lane = tid&63;
  const int row0 = blockIdx.x*64 + wave*16;
  const int arow = row0 + (lane&15);
  const int kb = (lane>>4)<<3;
  bf16x8 af[4];
  #pragma unroll
  for(int c=0;c<4;c++){
    const float4* p = (const float4*)(x + (size_t)arow*IND + c*32 + kb);
    af[c] = cvt8(p[0], p[1]);
  }
  const int mb = (lane>>4)<<2;
  const int hc = lane&15;
  #pragma unroll
  for(int nt=0;nt<16;nt++){
    f32x4 acc = {0.f,0.f,0.f,0.f};
    #pragma unroll
    for(int c=0;c<4;c++)
      acc = __builtin_amdgcn_mfma_f32_16x16x32_bf16(af[c], Ub[(nt*4+c)*64 + lane], acc, 0,0,0);
    const int h = nt*16 + hc;
    #pragma unroll
    for(int j=0;j<4;j++)
      uxz[(size_t)(row0 + mb + j)*HID + h] = (__bf16)acc[j];
  }
}

// ---------------------------------------------------------------------------
// Kernel 2: persistent scan, operand-swapped MFMA, 512 thr / 8 waves (2/SIMD).
// Tau GEMM in fp8 e4m3 (W_tau frags + z frags), real GEMM in bf16.
// LDS per buffer: z-fp8 frags 4KB + tanh-bf16 frags 8KB = 12KB, double-buffered.
// Per-CU state read/step: 8 waves * 12KB = 96KB (was 128KB) -> smaller LDS
// service window, which round-4 analysis showed is the binding resource.
// ---------------------------------------------------------------------------
__global__ __launch_bounds__(512,2) void scan_k(
    const float* __restrict__ W_real, const float* __restrict__ b_real,
    const float* __restrict__ W_tau,  const float* __restrict__ b_tau,
    const float* __restrict__ b_U,    __bf16* __restrict__ uxz){
  __shared__ char lds[24576];   // 2 bufs * (z8 4KB + tanh 8KB)
  const int tid = threadIdx.x, w = tid>>6, lane = tid&63;
  const int ln15 = lane&15, kg = lane>>4;
  const float L2E = 1.44269504088896340736f;

  // W_real as bf16 A-frags: m = w*32 + nt*16 + ln15, k = c*32 + kg*8
  // W_tau  as fp8  A-frags: same (m,k) mapping, 8 bytes/lane/chunk
  bf16x8 wr[2][8];
  long   wt8[2][8];
  #pragma unroll
  for(int nt=0;nt<2;nt++){
    const int n = w*32 + nt*16 + ln15;
    #pragma unroll
    for(int c=0;c<8;c++){
      const int k = c*32 + (kg<<3);
      const float4* pr = (const float4*)(W_real + n*HID + k);
      wr[nt][c] = cvt8(pr[0], pr[1]);
      const float4* pt = (const float4*)(W_tau + n*HID + k);
      const float4 t0 = pt[0], t1 = pt[1];
      const unsigned lo = (unsigned)pk_fp8x4(t0.x,t0.y,t0.z,t0.w);
      const unsigned hi = (unsigned)pk_fp8x4(t1.x,t1.y,t1.z,t1.w);
      wt8[nt][c] = (long)(((unsigned long)hi<<32) | lo);
    }
  }
  // Per-lane biases at owned h = w*32 + nt*16 + 4*kg + j
  float c1[2][4], bru[2][4];
  #pragma unroll
  for(int nt=0;nt<2;nt++)
    #pragma unroll
    for(int j=0;j<4;j++){
      const int h = w*32 + nt*16 + (kg<<2) + j;
      c1[nt][j]  = -L2E*b_tau[h];          // exp2 arg = fma(aT,-L2E,c1)
      bru[nt][j] = b_real[h] + b_U[h];
    }

  for(int s = tid; s < 1536; s += 512)
    ((float4*)lds)[s] = float4{0.f,0.f,0.f,0.f};
  __syncthreads();

  // read bases (within a buffer): z8 frag-major (chunk=512B), tanh (chunk=1024B)
  const int vr8 = lane<<3;
  const int vrT = 4096 + (lane<<4);
  // write bases:
  //  z8:   chunk w, byte = w*512 + (nt*2+(kg>>1))*128 + ln15*8 + (kg&1)*4  (b32)
  const int vw8 = (w<<9) + ((kg>>1)<<7) + (ln15<<3) + ((kg&1)<<2);
  //  tanh: chunk w, byte = 4096 + w*1024 + (kg>>1)*256 + ln15*16 + (kg&1)*8 + nt*512 (b64)
  const int vwT = 4096 + (w<<10) + ((kg>>1)<<8) + (ln15<<4) + ((kg&1)<<3);

  const int row  = blockIdx.x*16 + ln15;        // batch row this lane owns
  const int loff = row*HID + w*32 + (kg<<2);    // element offset, + nt*16

  float zr[2][4];
  #pragma unroll
  for(int nt=0;nt<2;nt++)
    #pragma unroll
    for(int j=0;j<4;j++) zr[nt][j]=0.f;

  uint2 uxr[2];
  #pragma unroll
  for(int nt=0;nt<2;nt++)
    uxr[nt] = *(const uint2*)(uxz + (size_t)loff + nt*16);

  int bo = 0;
  for(int t=0; t<T_STEPS; ++t){
    // prefetch ux[t+1] raw (b64, latency hidden under this step's compute)
    const int tn = (t < T_STEPS-1) ? t+1 : t;
    const __bf16* pn = uxz + (size_t)tn*(BATCH*HID);
    uint2 uxn[2];
    #pragma unroll
    for(int nt=0;nt<2;nt++)
      uxn[nt] = *(const uint2*)(pn + loff + nt*16);

    const char* rp8 = lds + bo + vr8;
    const char* rpT = lds + bo + vrT;
    f32x4 aT[2], aR[2];
    #pragma unroll
    for(int nt=0;nt<2;nt++){ aT[nt]=(f32x4){0,0,0,0}; aR[nt]=(f32x4){0,0,0,0}; }
    #pragma unroll
    for(int c=0;c<8;c++){
      const long   zf8 = *(const long*)(rp8 + c*512);
      const bf16x8 tf  = *(const bf16x8*)(rpT + c*1024);
      #pragma unroll
      for(int nt=0;nt<2;nt++){
        aT[nt] = __builtin_amdgcn_mfma_f32_16x16x32_fp8_fp8(wt8[nt][c], zf8, aT[nt], 0,0,0);
        aR[nt] = __builtin_amdgcn_mfma_f32_16x16x32_bf16(wr[nt][c], tf, aR[nt], 0,0,0);
      }
    }

    uint2 zpk[2], tpk[2];
    int   z8[2];
    #pragma unroll
    for(int nt=0;nt<2;nt++){
      float uxf[4];
      uxf[0] = __builtin_bit_cast(float, uxr[nt].x << 16);
      uxf[1] = __builtin_bit_cast(float, uxr[nt].x & 0xffff0000u);
      uxf[2] = __builtin_bit_cast(float, uxr[nt].y << 16);
      uxf[3] = __builtin_bit_cast(float, uxr[nt].y & 0xffff0000u);
      float znv[4];
      unsigned short zh[4], th[4];
      #pragma unroll
      for(int j=0;j<4;j++){
        const float g   = __builtin_amdgcn_exp2f(__builtin_fmaf(aT[nt][j], -L2E, c1[nt][j]));
        const float pre = (aR[nt][j] + bru[nt][j] + uxf[j]) - zr[nt][j];
        const float t0  = 0.1f*pre;
        const float zn  = __builtin_fmaf(t0, g, zr[nt][j] + t0);  // zr+0.1*pre*(1+g)
        zr[nt][j] = zn;
        znv[j] = zn;
        const float e2  = __builtin_amdgcn_exp2f(zn*(2.f*L2E));
        const float r   = __builtin_amdgcn_rcpf(e2 + 1.f);
        const float tv  = __builtin_fmaf(-2.f, r, 1.f);           // tanh(zn)
        zh[j] = __builtin_bit_cast(unsigned short, (__bf16)zn);
        th[j] = __builtin_bit_cast(unsigned short, (__bf16)tv);
      }
      z8[nt] = pk_fp8x4(znv[0], znv[1], znv[2], znv[3]);
      zpk[nt].x = (unsigned)zh[0] | ((unsigned)zh[1]<<16);
      zpk[nt].y = (unsigned)zh[2] | ((unsigned)zh[3]<<16);
      tpk[nt].x = (unsigned)th[0] | ((unsigned)th[1]<<16);
      tpk[nt].y = (unsigned)th[2] | ((unsigned)th[3]<<16);
      uxr[nt] = uxn[nt];
    }

    char* wp = lds + (bo^12288);
    #pragma unroll
    for(int nt=0;nt<2;nt++){
      *(int*)  (wp + vw8 + nt*256) = z8[nt];
      *(uint2*)(wp + vwT + nt*512) = tpk[nt];
    }
    __syncthreads();

    // zr_t (bf16) for y_gemm: issued after the barrier; next barrier drains it
    __bf16* ps = uxz + (size_t)t*(BATCH*HID);
    #pragma unroll
    for(int nt=0;nt<2;nt++)
      *(uint2*)(ps + loff + nt*16) = zpk[nt];

    bo ^= 12288;
  }
}

// ---------------------------------------------------------------------------
// Kernel 3: y[m,o] = sum_h zr[m,h] * W_out[o,h] + b_out[o]   (fp32 out)
// ---------------------------------------------------------------------------
__global__ __launch_bounds__(256) void y_gemm(
    const __bf16* __restrict__ zrbuf, const float* __restrict__ W_out,
    const float* __restrict__ b_out, float* __restrict__ y){
  __shared__ bf16x8 Wo[2048];   // 4 nt * 8 c * 64 lanes, 32 KB
  const int tid = threadIdx.x;
  for(int s=tid; s<2048; s+=256){
    const int l = s&63, c = (s>>6)&7, nt = s>>9;
    const int n = nt*16 + (l&15), k = c*32 + ((l>>4)<<3);
    const float4* p = (const float4*)(W_out + n*HID + k);
    Wo[s] = cvt8(p[0], p[1]);
  }
  __syncthreads();
  const int wave = tid>>6, lane = tid&63;
  const int row0 = blockIdx.x*64 + wave*16;
  const int kb = (lane>>4)<<3;
  bf16x8 af[8];
  #pragma unroll
  for(int c=0;c<8;c++)
    af[c] = *(const bf16x8*)(zrbuf + (size_t)(row0 + (lane&15))*HID + c*32 + kb);
  f32x4 acc[4];
  #pragma unroll
  for(int nt=0;nt<4;nt++) acc[nt] = (f32x4){0,0,0,0};
  #pragma unroll
  for(int nt=0;nt<4;nt++)
    #pragma unroll
    for(int c=0;c<8;c++)
      acc[nt] = __builtin_amdgcn_mfma_f32_16x16x32_bf16(af[c], Wo[(nt*8+c)*64 + lane], acc[nt], 0,0,0);
  const int mb = (lane>>4)<<2, oc = lane&15;
  #pragma unroll
  for(int nt=0;nt<4;nt++){
    const float bo = b_out[nt*16 + oc];
    #pragma unroll
    for(int j=0;j<4;j++)
      y[(size_t)(row0 + mb + j)*OUTD + nt*16 + oc] = acc[nt][j] + bo;
  }
}

extern "C" void kernel_launch(void* const* d_in, const int* in_sizes, int n_in,
                              void* d_out, int out_size, void* d_ws, size_t ws_size,
                              hipStream_t stream){
  const float* x      = (const float*)d_in[0];
  const float* W_real = (const float*)d_in[1];
  const float* b_real = (const float*)d_in[2];
  // d_in[3] = W_imag, d_in[4] = b_imag : dead (zi never affects zr or y)
  const float* U      = (const float*)d_in[5];
  const float* b_U    = (const float*)d_in[6];
  const float* W_tau  = (const float*)d_in[7];
  const float* b_tau  = (const float*)d_in[8];
  const float* W_out  = (const float*)d_in[9];
  const float* b_out  = (const float*)d_in[10];
  __bf16* uxz = (__bf16*)d_ws;   // T*B*HID bf16 = 128 MiB: holds Ux, then zr_t

  ux_gemm<<<dim3((T_STEPS*BATCH)/64), dim3(256), 0, stream>>>(x, U, uxz);
  scan_k <<<dim3(BATCH/16),           dim3(512), 0, stream>>>(W_real, b_real, W_tau, b_tau, b_U, uxz);
  y_gemm <<<dim3((T_STEPS*BATCH)/64), dim3(256), 0, stream>>>(uxz, W_out, b_out, (float*)d_out);
}

// Round 6
// 1212.400 us; speedup vs baseline: 1.0673x; 1.0673x over previous
//
#include <hip/hip_runtime.h>

#define T_STEPS 1024
#define BATCH   256
#define IND     128
#define HID     256
#define OUTD    64

typedef float  f32x4  __attribute__((ext_vector_type(4)));
typedef __bf16 bf16x8 __attribute__((ext_vector_type(8)));

__device__ __forceinline__ bf16x8 cvt8(float4 a, float4 b){
  bf16x8 v;
  v[0]=(__bf16)a.x; v[1]=(__bf16)a.y; v[2]=(__bf16)a.z; v[3]=(__bf16)a.w;
  v[4]=(__bf16)b.x; v[5]=(__bf16)b.y; v[6]=(__bf16)b.z; v[7]=(__bf16)b.w;
  return v;
}
__device__ __forceinline__ bf16x8 cvt8s(float4 a, float4 b, float s){
  bf16x8 v;
  v[0]=(__bf16)(s*a.x); v[1]=(__bf16)(s*a.y); v[2]=(__bf16)(s*a.z); v[3]=(__bf16)(s*a.w);
  v[4]=(__bf16)(s*b.x); v[5]=(__bf16)(s*b.y); v[6]=(__bf16)(s*b.z); v[7]=(__bf16)(s*b.w);
  return v;
}
// pack 4 f32 -> 4 fp8(e4m3) bytes in one dword
__device__ __forceinline__ int pk_fp8x4(float a, float b, float c, float d){
  int r = __builtin_amdgcn_cvt_pk_fp8_f32(a, b, 0, false);
  r     = __builtin_amdgcn_cvt_pk_fp8_f32(c, d, r, true);
  return r;
}
__device__ __forceinline__ float bflo(unsigned u){ return __builtin_bit_cast(float, u<<16); }
__device__ __forceinline__ float bfhi(unsigned u){ return __builtin_bit_cast(float, u & 0xffff0000u); }

// permuted h-index used in the uxz workspace:
// h = w*32+nt*16+kg*4+j  ->  ph = w*32 + kg*8 + nt*4 + j
// (scan lane (w,kg,ln15) owns ph = w*32+kg*8 .. +7 : ONE contiguous 16B slot)

// ---------------------------------------------------------------------------
// Kernel 1: uxz'[t,b,ph] = bf16( 0.1*(x@U^T + b_U + b_real) )  (swapped MFMA:
// D[h][batch] -> lane owns 4 consecutive h for one row -> packed b64 stores)
// ---------------------------------------------------------------------------
__global__ __launch_bounds__(256) void ux_gemm(const float* __restrict__ x,
                                               const float* __restrict__ U,
                                               const float* __restrict__ b_real,
                                               const float* __restrict__ b_U,
                                               __bf16* __restrict__ uxz){
  __shared__ bf16x8 Ub[4096];   // [16 nt][4 c][64 lanes] A-frags, 64 KB
  const int tid = threadIdx.x;
  for(int s = tid; s < 4096; s += 256){
    const int l = s & 63, c = (s>>6)&3, nt = s>>8;
    const int n = nt*16 + (l&15), k = c*32 + ((l>>4)<<3);
    const float4* p = (const float4*)(U + n*IND + k);
    Ub[s] = cvt8(p[0], p[1]);
  }
  __syncthreads();
  const int wave = tid>>6, lane = tid&63, ln15 = lane&15, kg = lane>>4;
  const int row0 = blockIdx.x*64 + wave*16;
  const int grow = row0 + ln15;
  bf16x8 xf[4];
  #pragma unroll
  for(int c=0;c<4;c++){
    const float4* p = (const float4*)(x + (size_t)grow*IND + c*32 + (kg<<3));
    xf[c] = cvt8(p[0], p[1]);
  }
  #pragma unroll
  for(int nt=0;nt<16;nt++){
    f32x4 acc = {0.f,0.f,0.f,0.f};
    #pragma unroll
    for(int c=0;c<4;c++)
      acc = __builtin_amdgcn_mfma_f32_16x16x32_bf16(Ub[(nt*4+c)*64 + lane], xf[c], acc, 0,0,0);
    const int hb = nt*16 + (kg<<2);
    const float4 br = *(const float4*)(b_real + hb);
    const float4 bu = *(const float4*)(b_U + hb);
    const float brv[4] = {br.x,br.y,br.z,br.w};
    const float buv[4] = {bu.x,bu.y,bu.z,bu.w};
    unsigned short hs[4];
    #pragma unroll
    for(int j=0;j<4;j++)
      hs[j] = __builtin_bit_cast(unsigned short, (__bf16)(0.1f*(acc[j] + brv[j] + buv[j])));
    uint2 pk;
    pk.x = (unsigned)hs[0] | ((unsigned)hs[1]<<16);
    pk.y = (unsigned)hs[2] | ((unsigned)hs[3]<<16);
    *(uint2*)(uxz + (size_t)grow*HID + ((nt>>1)<<5) + (kg<<3) + ((nt&1)<<2)) = pk;
  }
}

// ---------------------------------------------------------------------------
// Kernel 2: persistent scan. 16 WGs x 512 thr (8 waves, 2/SIMD).
// All constant folds done upstream: uxz holds 0.1*(Ux+b_U+b_real);
// W_real frags pre-scaled 0.1; W_tau frags = fp8(16*W_tau) (normal-range);
// aR init = ux slot, aT init = 16*b_tau (C-operand folds).
// LDS: z8 pair-blocks (4x1KB -> 4xb128 reads) + tanh bf16 (8KB), dbuf.
// Global: 1xb128 load (prefetch t+1) + 1xb128 store (zr_t) per step.
// ---------------------------------------------------------------------------
__global__ __launch_bounds__(512,2) void scan_k(
    const float* __restrict__ W_real, const float* __restrict__ W_tau,
    const float* __restrict__ b_tau,  __bf16* __restrict__ uxz){
  __shared__ char lds[24576];   // 2 bufs * (z8 4KB + tanh 8KB)
  const int tid = threadIdx.x, w = tid>>6, lane = tid&63;
  const int ln15 = lane&15, kg = lane>>4;
  const float KNEG = -0.09016844f;           // -log2(e)/16
  const float TL2E = 2.88539008f;            // 2*log2(e)

  bf16x8 wr[2][8];
  long   wt8[2][8];
  #pragma unroll
  for(int nt=0;nt<2;nt++){
    const int n = w*32 + nt*16 + ln15;
    #pragma unroll
    for(int c=0;c<8;c++){
      const int k = c*32 + (kg<<3);
      const float4* pr = (const float4*)(W_real + n*HID + k);
      wr[nt][c] = cvt8s(pr[0], pr[1], 0.1f);
      const float4* pt = (const float4*)(W_tau + n*HID + k);
      const float4 t0 = pt[0], t1 = pt[1];
      const unsigned lo = (unsigned)pk_fp8x4(16.f*t0.x,16.f*t0.y,16.f*t0.z,16.f*t0.w);
      const unsigned hi = (unsigned)pk_fp8x4(16.f*t1.x,16.f*t1.y,16.f*t1.z,16.f*t1.w);
      wt8[nt][c] = (long)(((unsigned long)hi<<32) | lo);
    }
  }
  f32x4 bt16[2];
  #pragma unroll
  for(int nt=0;nt<2;nt++){
    const float4 bt = *(const float4*)(b_tau + w*32 + nt*16 + (kg<<2));
    bt16[nt] = (f32x4){16.f*bt.x, 16.f*bt.y, 16.f*bt.z, 16.f*bt.w};
  }

  for(int s = tid; s < 1536; s += 512)
    ((float4*)lds)[s] = float4{0.f,0.f,0.f,0.f};
  __syncthreads();

  // read bases: z8 pair-block p at p*1024 + lane*16 (b128, linear);
  //             tanh chunk c at 4096 + c*1024 + lane*16 (b128, linear)
  const int vrZ = lane<<4;
  const int vrT = 4096 + (lane<<4);
  // write offsets (per nt)
  int vwZ[2], vwT[2];
  #pragma unroll
  for(int nt=0;nt<2;nt++){
    vwZ[nt] = ((w>>1)<<10) + (((nt*2+(kg>>1))*16 + ln15)<<4) + ((w&1)<<3) + ((kg&1)<<2);
    vwT[nt] = 4096 + (w<<10) + (nt<<9) + ((kg>>1)<<8) + (ln15<<4) + ((kg&1)<<3);
  }

  const int row  = blockIdx.x*16 + ln15;
  const int loff = row*HID + (w<<5) + (kg<<3);   // lane's contiguous 8-elem slot

  float zr[2][4], szr[2][4];
  #pragma unroll
  for(int nt=0;nt<2;nt++)
    #pragma unroll
    for(int j=0;j<4;j++){ zr[nt][j]=0.f; szr[nt][j]=0.f; }

  uint4 uxr = *(const uint4*)(uxz + loff);

  int bo = 0;
  for(int t=0; t<T_STEPS; ++t){
    const int tn = (t < T_STEPS-1) ? t+1 : t;
    const uint4 uxn = *(const uint4*)(uxz + (size_t)tn*(BATCH*HID) + loff);

    f32x4 aT[2], aR[2];
    aT[0] = bt16[0]; aT[1] = bt16[1];
    aR[0] = (f32x4){bflo(uxr.x), bfhi(uxr.x), bflo(uxr.y), bfhi(uxr.y)};
    aR[1] = (f32x4){bflo(uxr.z), bfhi(uxr.z), bflo(uxr.w), bfhi(uxr.w)};

    #pragma unroll
    for(int p=0;p<4;p++){
      const uint4  zp = *(const uint4*)(lds + bo + vrZ + p*1024);
      const bf16x8 ta = *(const bf16x8*)(lds + bo + vrT + (2*p)*1024);
      const bf16x8 tb = *(const bf16x8*)(lds + bo + vrT + (2*p+1)*1024);
      const long zlo = (long)(((unsigned long)zp.y<<32) | zp.x);
      const long zhi = (long)(((unsigned long)zp.w<<32) | zp.z);
      #pragma unroll
      for(int nt=0;nt<2;nt++){
        aT[nt] = __builtin_amdgcn_mfma_f32_16x16x32_fp8_fp8(wt8[nt][2*p],   zlo, aT[nt], 0,0,0);
        aT[nt] = __builtin_amdgcn_mfma_f32_16x16x32_fp8_fp8(wt8[nt][2*p+1], zhi, aT[nt], 0,0,0);
        aR[nt] = __builtin_amdgcn_mfma_f32_16x16x32_bf16(wr[nt][2*p],   ta, aR[nt], 0,0,0);
        aR[nt] = __builtin_amdgcn_mfma_f32_16x16x32_bf16(wr[nt][2*p+1], tb, aR[nt], 0,0,0);
      }
    }

    uint2 tpk[2];
    int   z8[2];
    uint4 zst;
    #pragma unroll
    for(int nt=0;nt<2;nt++){
      float znv[4];
      unsigned short zh[4], th[4];
      #pragma unroll
      for(int j=0;j<4;j++){
        const float g   = __builtin_amdgcn_exp2f(aT[nt][j]*KNEG);   // e^{-x}
        const float d   = aR[nt][j] - szr[nt][j];                   // 0.1*pre
        const float s   = zr[nt][j] + d;
        const float zn  = __builtin_fmaf(d, g, s);                  // zr + d*(1+g)
        zr[nt][j]  = zn;
        szr[nt][j] = 0.1f*zn;
        znv[j] = zn;
        const float e2  = __builtin_amdgcn_exp2f(zn*TL2E);
        const float r   = __builtin_amdgcn_rcpf(e2 + 1.f);
        const float tv  = __builtin_fmaf(-2.f, r, 1.f);             // tanh(zn)
        zh[j] = __builtin_bit_cast(unsigned short, (__bf16)zn);
        th[j] = __builtin_bit_cast(unsigned short, (__bf16)tv);
      }
      z8[nt]  = pk_fp8x4(znv[0], znv[1], znv[2], znv[3]);
      tpk[nt].x = (unsigned)th[0] | ((unsigned)th[1]<<16);
      tpk[nt].y = (unsigned)th[2] | ((unsigned)th[3]<<16);
      if(nt==0){ zst.x = (unsigned)zh[0] | ((unsigned)zh[1]<<16);
                 zst.y = (unsigned)zh[2] | ((unsigned)zh[3]<<16); }
      else     { zst.z = (unsigned)zh[0] | ((unsigned)zh[1]<<16);
                 zst.w = (unsigned)zh[2] | ((unsigned)zh[3]<<16); }
    }

    char* wp = lds + (bo^12288);
    #pragma unroll
    for(int nt=0;nt<2;nt++){
      *(int*)  (wp + vwZ[nt]) = z8[nt];
      *(uint2*)(wp + vwT[nt]) = tpk[nt];
    }
    uxr = uxn;
    __syncthreads();

    *(uint4*)(uxz + (size_t)t*(BATCH*HID) + loff) = zst;   // zr_t for y_gemm
    bo ^= 12288;
  }
}

// ---------------------------------------------------------------------------
// Kernel 3: y[m,o] = sum_h zr[m,h] * W_out[o,h] + b_out[o]   (fp32 out)
// zr read from the permuted uxz layout (2xb64 per 32-wide k-chunk).
// ---------------------------------------------------------------------------
__global__ __launch_bounds__(256) void y_gemm(
    const __bf16* __restrict__ zrbuf, const float* __restrict__ W_out,
    const float* __restrict__ b_out, float* __restrict__ y){
  __shared__ bf16x8 Wo[2048];   // [4 nt][8 c][64 lanes], 32 KB
  const int tid = threadIdx.x;
  for(int s=tid; s<2048; s+=256){
    const int l = s&63, c = (s>>6)&7, nt = s>>9;
    const int n = nt*16 + (l&15), k = c*32 + ((l>>4)<<3);
    const float4* p = (const float4*)(W_out + n*HID + k);
    Wo[s] = cvt8(p[0], p[1]);
  }
  __syncthreads();
  const int wave = tid>>6, lane = tid&63, kg = lane>>4;
  const int row0 = blockIdx.x*64 + wave*16;
  // permuted offsets of the two 4-element groups of (k = c*32 + kg*8 + e)
  const int pA = (((2*kg  )&3)<<3) + ((kg>>1)<<2);
  const int pB = (((2*kg+1)&3)<<3) + ((kg>>1)<<2);
  const __bf16* zb = zrbuf + (size_t)(row0 + (lane&15))*HID;
  bf16x8 af[8];
  #pragma unroll
  for(int c=0;c<8;c++){
    const uint2 lo = *(const uint2*)(zb + c*32 + pA);
    const uint2 hi = *(const uint2*)(zb + c*32 + pB);
    af[c] = __builtin_bit_cast(bf16x8, (uint4){lo.x, lo.y, hi.x, hi.y});
  }
  f32x4 acc[4];
  #pragma unroll
  for(int nt=0;nt<4;nt++) acc[nt] = (f32x4){0,0,0,0};
  #pragma unroll
  for(int nt=0;nt<4;nt++)
    #pragma unroll
    for(int c=0;c<8;c++)
      acc[nt] = __builtin_amdgcn_mfma_f32_16x16x32_bf16(af[c], Wo[(nt*8+c)*64 + lane], acc[nt], 0,0,0);
  const int mb = (lane>>4)<<2, oc = lane&15;
  #pragma unroll
  for(int nt=0;nt<4;nt++){
    const float bo = b_out[nt*16 + oc];
    #pragma unroll
    for(int j=0;j<4;j++)
      y[(size_t)(row0 + mb + j)*OUTD + nt*16 + oc] = acc[nt][j] + bo;
  }
}

extern "C" void kernel_launch(void* const* d_in, const int* in_sizes, int n_in,
                              void* d_out, int out_size, void* d_ws, size_t ws_size,
                              hipStream_t stream){
  const float* x      = (const float*)d_in[0];
  const float* W_real = (const float*)d_in[1];
  const float* b_real = (const float*)d_in[2];
  // d_in[3] = W_imag, d_in[4] = b_imag : dead (zi never affects zr or y)
  const float* U      = (const float*)d_in[5];
  const float* b_U    = (const float*)d_in[6];
  const float* W_tau  = (const float*)d_in[7];
  const float* b_tau  = (const float*)d_in[8];
  const float* W_out  = (const float*)d_in[9];
  const float* b_out  = (const float*)d_in[10];
  __bf16* uxz = (__bf16*)d_ws;   // T*B*HID bf16, permuted-h layout:
                                 // holds 0.1*(Ux+b) then zr_t

  ux_gemm<<<dim3((T_STEPS*BATCH)/64), dim3(256), 0, stream>>>(x, U, b_real, b_U, uxz);
  scan_k <<<dim3(BATCH/16),           dim3(512), 0, stream>>>(W_real, W_tau, b_tau, uxz);
  y_gemm <<<dim3((T_STEPS*BATCH)/64), dim3(256), 0, stream>>>(uxz, W_out, b_out, (float*)d_out);
}

// Round 7
// 1176.859 us; speedup vs baseline: 1.0996x; 1.0302x over previous
//
#include <hip/hip_runtime.h>

#define T_STEPS 1024
#define BATCH   256
#define IND     128
#define HID     256
#define OUTD    64

typedef float  f32x4  __attribute__((ext_vector_type(4)));
typedef __bf16 bf16x8 __attribute__((ext_vector_type(8)));

__device__ __forceinline__ bf16x8 cvt8(float4 a, float4 b){
  bf16x8 v;
  v[0]=(__bf16)a.x; v[1]=(__bf16)a.y; v[2]=(__bf16)a.z; v[3]=(__bf16)a.w;
  v[4]=(__bf16)b.x; v[5]=(__bf16)b.y; v[6]=(__bf16)b.z; v[7]=(__bf16)b.w;
  return v;
}
// pack 4 f32 -> 4 fp8(e4m3) bytes in one dword
__device__ __forceinline__ int pk_fp8x4(float a, float b, float c, float d){
  int r = __builtin_amdgcn_cvt_pk_fp8_f32(a, b, 0, false);
  r     = __builtin_amdgcn_cvt_pk_fp8_f32(c, d, r, true);
  return r;
}
__device__ __forceinline__ float bflo(unsigned u){ return __builtin_bit_cast(float, u<<16); }
__device__ __forceinline__ float bfhi(unsigned u){ return __builtin_bit_cast(float, u & 0xffff0000u); }

// permuted h-index in the uxz workspace: h = w*32+nt*16+kg*4+j -> ph = w*32+kg*8+nt*4+j
// (scan lane (w,kg,ln15) owns ph = w*32+kg*8 .. +7 : ONE contiguous 16B slot)

// ---------------------------------------------------------------------------
// Kernel 1: uxz'[t,b,ph] = bf16( 3.2*(x@U^T + b_U + b_real) )
// (3.2 = 32*0.1: scan's W_real is stored fp8(3.2*W), and aR_total/32 recovers
//  0.1*(W.tanh + Ux + b); swapped MFMA -> packed b64 permuted stores)
// ---------------------------------------------------------------------------
__global__ __launch_bounds__(256) void ux_gemm(const float* __restrict__ x,
                                               const float* __restrict__ U,
                                               const float* __restrict__ b_real,
                                               const float* __restrict__ b_U,
                                               __bf16* __restrict__ uxz){
  __shared__ bf16x8 Ub[4096];   // [16 nt][4 c][64 lanes] A-frags, 64 KB
  const int tid = threadIdx.x;
  for(int s = tid; s < 4096; s += 256){
    const int l = s & 63, c = (s>>6)&3, nt = s>>8;
    const int n = nt*16 + (l&15), k = c*32 + ((l>>4)<<3);
    const float4* p = (const float4*)(U + n*IND + k);
    Ub[s] = cvt8(p[0], p[1]);
  }
  __syncthreads();
  const int wave = tid>>6, lane = tid&63, ln15 = lane&15, kg = lane>>4;
  const int row0 = blockIdx.x*64 + wave*16;
  const int grow = row0 + ln15;
  bf16x8 xf[4];
  #pragma unroll
  for(int c=0;c<4;c++){
    const float4* p = (const float4*)(x + (size_t)grow*IND + c*32 + (kg<<3));
    xf[c] = cvt8(p[0], p[1]);
  }
  #pragma unroll
  for(int nt=0;nt<16;nt++){
    f32x4 acc = {0.f,0.f,0.f,0.f};
    #pragma unroll
    for(int c=0;c<4;c++)
      acc = __builtin_amdgcn_mfma_f32_16x16x32_bf16(Ub[(nt*4+c)*64 + lane], xf[c], acc, 0,0,0);
    const int hb = nt*16 + (kg<<2);
    const float4 br = *(const float4*)(b_real + hb);
    const float4 bu = *(const float4*)(b_U + hb);
    const float brv[4] = {br.x,br.y,br.z,br.w};
    const float buv[4] = {bu.x,bu.y,bu.z,bu.w};
    unsigned short hs[4];
    #pragma unroll
    for(int j=0;j<4;j++)
      hs[j] = __builtin_bit_cast(unsigned short, (__bf16)(3.2f*(acc[j] + brv[j] + buv[j])));
    uint2 pk;
    pk.x = (unsigned)hs[0] | ((unsigned)hs[1]<<16);
    pk.y = (unsigned)hs[2] | ((unsigned)hs[3]<<16);
    *(uint2*)(uxz + (size_t)grow*HID + ((nt>>1)<<5) + (kg<<3) + ((nt&1)<<2)) = pk;
  }
}

// ---------------------------------------------------------------------------
// Kernel 2: persistent scan. 16 WGs x 512 thr (8 waves, 2/SIMD).
// ALL-fp8 LDS state: z8 (4KB) + tanh8 (4KB) per buffer, double-buffered (16KB).
// Per-wave reads: 8 x ds_read_b128 (was 12); writes: 4 x b32.
// Weights: wr8 = fp8(3.2*W_real), wt8 = fp8(16*W_tau): 64 VGPR total.
// Folds: aT C-init = 16*b_tau; aR C-init = ux' = 3.2*(Ux+b_U+b_real);
//        d = 0.1*pre = fma(aR_total, 1/32, -0.1*zr).
// Split accumulators (a/b halves of k) -> 8 MFMA chains x 4-deep.
// Static 2-step-unrolled t loop (compile-time buffer offsets).
// ---------------------------------------------------------------------------
__global__ __launch_bounds__(512,2) void scan_k(
    const float* __restrict__ W_real, const float* __restrict__ W_tau,
    const float* __restrict__ b_tau,  __bf16* __restrict__ uxz){
  __shared__ char lds[16384];   // 2 bufs * (z8 4KB + t8 4KB)
  const int tid = threadIdx.x, w = tid>>6, lane = tid&63;
  const int ln15 = lane&15, kg = lane>>4;
  const float KNEG = -0.09016844f;           // -log2(e)/16
  const float TL2E = 2.88539008f;            // 2*log2(e)

  long wr8[2][8], wt8[2][8];
  #pragma unroll
  for(int nt=0;nt<2;nt++){
    const int n = w*32 + nt*16 + ln15;
    #pragma unroll
    for(int c=0;c<8;c++){
      const int k = c*32 + (kg<<3);
      const float4 r0 = *(const float4*)(W_real + n*HID + k);
      const float4 r1 = *(const float4*)(W_real + n*HID + k + 4);
      const unsigned rlo = (unsigned)pk_fp8x4(3.2f*r0.x,3.2f*r0.y,3.2f*r0.z,3.2f*r0.w);
      const unsigned rhi = (unsigned)pk_fp8x4(3.2f*r1.x,3.2f*r1.y,3.2f*r1.z,3.2f*r1.w);
      wr8[nt][c] = (long)(((unsigned long)rhi<<32) | rlo);
      const float4 t0 = *(const float4*)(W_tau + n*HID + k);
      const float4 t1 = *(const float4*)(W_tau + n*HID + k + 4);
      const unsigned tlo = (unsigned)pk_fp8x4(16.f*t0.x,16.f*t0.y,16.f*t0.z,16.f*t0.w);
      const unsigned thi = (unsigned)pk_fp8x4(16.f*t1.x,16.f*t1.y,16.f*t1.z,16.f*t1.w);
      wt8[nt][c] = (long)(((unsigned long)thi<<32) | tlo);
    }
  }
  f32x4 bt16[2];
  #pragma unroll
  for(int nt=0;nt<2;nt++){
    const float4 bt = *(const float4*)(b_tau + w*32 + nt*16 + (kg<<2));
    bt16[nt] = (f32x4){16.f*bt.x, 16.f*bt.y, 16.f*bt.z, 16.f*bt.w};
  }

  for(int s = tid; s < 1024; s += 512)
    ((float4*)lds)[s] = float4{0.f,0.f,0.f,0.f};
  __syncthreads();

  // producer write offset (z8 region; t8 = +4096). Derivation (verified R6):
  // h = w*32+nt*16+kg*4+j -> chunk c=w, frag lane' = (nt*2+(kg>>1))*16+ln15,
  // byte = (w>>1)*1024 + lane'*16 + (w&1)*8 + (kg&1)*4  (+j, contiguous b32)
  int vwZ[2];
  #pragma unroll
  for(int nt=0;nt<2;nt++)
    vwZ[nt] = ((w>>1)<<10) + (((nt*2+(kg>>1))*16 + ln15)<<4) + ((w&1)<<3) + ((kg&1)<<2);

  const int row  = blockIdx.x*16 + ln15;
  const int loff = row*HID + (w<<5) + (kg<<3);   // lane's contiguous 8-elem slot

  float zr[2][4];
  #pragma unroll
  for(int nt=0;nt<2;nt++)
    #pragma unroll
    for(int j=0;j<4;j++) zr[nt][j]=0.f;

  uint4 uxr = *(const uint4*)(uxz + loff);

  auto step = [&](const int BO, const int BN, const int T){
    const int tn = (T < T_STEPS-1) ? T+1 : T;
    const uint4 uxn = *(const uint4*)(uxz + (size_t)tn*(BATCH*HID) + loff);

    f32x4 aTa[2], aTb[2], aRa[2], aRb[2];
    aTa[0] = bt16[0]; aTa[1] = bt16[1];
    aRa[0] = (f32x4){bflo(uxr.x), bfhi(uxr.x), bflo(uxr.y), bfhi(uxr.y)};
    aRa[1] = (f32x4){bflo(uxr.z), bfhi(uxr.z), bflo(uxr.w), bfhi(uxr.w)};
    #pragma unroll
    for(int nt=0;nt<2;nt++){ aTb[nt]=(f32x4){0,0,0,0}; aRb[nt]=(f32x4){0,0,0,0}; }

    #pragma unroll
    for(int p=0;p<4;p++){
      const uint4 zp = *(const uint4*)(lds + BO + (lane<<4) + p*1024);
      const uint4 tp = *(const uint4*)(lds + BO + 4096 + (lane<<4) + p*1024);
      const long zlo = (long)(((unsigned long)zp.y<<32) | zp.x);
      const long zhi = (long)(((unsigned long)zp.w<<32) | zp.z);
      const long tlo = (long)(((unsigned long)tp.y<<32) | tp.x);
      const long thi = (long)(((unsigned long)tp.w<<32) | tp.z);
      #pragma unroll
      for(int nt=0;nt<2;nt++){
        f32x4& dT = (p<2) ? aTa[nt] : aTb[nt];
        f32x4& dR = (p<2) ? aRa[nt] : aRb[nt];
        dT = __builtin_amdgcn_mfma_f32_16x16x32_fp8_fp8(wt8[nt][2*p],   zlo, dT, 0,0,0);
        dT = __builtin_amdgcn_mfma_f32_16x16x32_fp8_fp8(wt8[nt][2*p+1], zhi, dT, 0,0,0);
        dR = __builtin_amdgcn_mfma_f32_16x16x32_fp8_fp8(wr8[nt][2*p],   tlo, dR, 0,0,0);
        dR = __builtin_amdgcn_mfma_f32_16x16x32_fp8_fp8(wr8[nt][2*p+1], thi, dR, 0,0,0);
      }
    }

    int z8w[2], t8w[2];
    uint4 zst;
    #pragma unroll
    for(int nt=0;nt<2;nt++){
      const f32x4 aT = aTa[nt] + aTb[nt];
      const f32x4 aR = aRa[nt] + aRb[nt];
      float znv[4], tvv[4];
      unsigned short zh[4];
      #pragma unroll
      for(int j=0;j<4;j++){
        const float g  = __builtin_amdgcn_exp2f(aT[j]*KNEG);        // e^{-x}
        const float zm = -0.1f*zr[nt][j];
        const float d  = __builtin_fmaf(aR[j], 0.03125f, zm);       // 0.1*pre
        const float s  = zr[nt][j] + d;
        const float zn = __builtin_fmaf(d, g, s);                   // zr + d*(1+g)
        zr[nt][j] = zn;
        znv[j] = zn;
        const float e2 = __builtin_amdgcn_exp2f(zn*TL2E);
        const float r  = __builtin_amdgcn_rcpf(e2 + 1.f);
        tvv[j] = __builtin_fmaf(-2.f, r, 1.f);                      // tanh(zn)
        zh[j]  = __builtin_bit_cast(unsigned short, (__bf16)zn);
      }
      z8w[nt] = pk_fp8x4(znv[0], znv[1], znv[2], znv[3]);
      t8w[nt] = pk_fp8x4(tvv[0], tvv[1], tvv[2], tvv[3]);
      if(nt==0){ zst.x = (unsigned)zh[0] | ((unsigned)zh[1]<<16);
                 zst.y = (unsigned)zh[2] | ((unsigned)zh[3]<<16); }
      else     { zst.z = (unsigned)zh[0] | ((unsigned)zh[1]<<16);
                 zst.w = (unsigned)zh[2] | ((unsigned)zh[3]<<16); }
    }

    #pragma unroll
    for(int nt=0;nt<2;nt++){
      *(int*)(lds + BN + vwZ[nt])        = z8w[nt];
      *(int*)(lds + BN + 4096 + vwZ[nt]) = t8w[nt];
    }
    uxr = uxn;
    __syncthreads();
    *(uint4*)(uxz + (size_t)T*(BATCH*HID) + loff) = zst;   // zr_t for y_gemm
  };

  for(int tt=0; tt<T_STEPS; tt+=2){
    step(0,    8192, tt);
    step(8192, 0,    tt+1);
  }
}

// ---------------------------------------------------------------------------
// Kernel 3: y[m,o] = sum_h zr[m,h] * W_out[o,h] + b_out[o]   (fp32 out)
// zr read from the permuted uxz layout (2xb64 per 32-wide k-chunk).
// ---------------------------------------------------------------------------
__global__ __launch_bounds__(256) void y_gemm(
    const __bf16* __restrict__ zrbuf, const float* __restrict__ W_out,
    const float* __restrict__ b_out, float* __restrict__ y){
  __shared__ bf16x8 Wo[2048];   // [4 nt][8 c][64 lanes], 32 KB
  const int tid = threadIdx.x;
  for(int s=tid; s<2048; s+=256){
    const int l = s&63, c = (s>>6)&7, nt = s>>9;
    const int n = nt*16 + (l&15), k = c*32 + ((l>>4)<<3);
    const float4* p = (const float4*)(W_out + n*HID + k);
    Wo[s] = cvt8(p[0], p[1]);
  }
  __syncthreads();
  const int wave = tid>>6, lane = tid&63, kg = lane>>4;
  const int row0 = blockIdx.x*64 + wave*16;
  const int pA = (((2*kg  )&3)<<3) + ((kg>>1)<<2);
  const int pB = (((2*kg+1)&3)<<3) + ((kg>>1)<<2);
  const __bf16* zb = zrbuf + (size_t)(row0 + (lane&15))*HID;
  bf16x8 af[8];
  #pragma unroll
  for(int c=0;c<8;c++){
    const uint2 lo = *(const uint2*)(zb + c*32 + pA);
    const uint2 hi = *(const uint2*)(zb + c*32 + pB);
    af[c] = __builtin_bit_cast(bf16x8, (uint4){lo.x, lo.y, hi.x, hi.y});
  }
  f32x4 acc[4];
  #pragma unroll
  for(int nt=0;nt<4;nt++) acc[nt] = (f32x4){0,0,0,0};
  #pragma unroll
  for(int nt=0;nt<4;nt++)
    #pragma unroll
    for(int c=0;c<8;c++)
      acc[nt] = __builtin_amdgcn_mfma_f32_16x16x32_bf16(af[c], Wo[(nt*8+c)*64 + lane], acc[nt], 0,0,0);
  const int mb = (lane>>4)<<2, oc = lane&15;
  #pragma unroll
  for(int nt=0;nt<4;nt++){
    const float bo = b_out[nt*16 + oc];
    #pragma unroll
    for(int j=0;j<4;j++)
      y[(size_t)(row0 + mb + j)*OUTD + nt*16 + oc] = acc[nt][j] + bo;
  }
}

extern "C" void kernel_launch(void* const* d_in, const int* in_sizes, int n_in,
                              void* d_out, int out_size, void* d_ws, size_t ws_size,
                              hipStream_t stream){
  const float* x      = (const float*)d_in[0];
  const float* W_real = (const float*)d_in[1];
  const float* b_real = (const float*)d_in[2];
  // d_in[3] = W_imag, d_in[4] = b_imag : dead (zi never affects zr or y)
  const float* U      = (const float*)d_in[5];
  const float* b_U    = (const float*)d_in[6];
  const float* W_tau  = (const float*)d_in[7];
  const float* b_tau  = (const float*)d_in[8];
  const float* W_out  = (const float*)d_in[9];
  const float* b_out  = (const float*)d_in[10];
  __bf16* uxz = (__bf16*)d_ws;   // T*B*HID bf16, permuted-h layout:
                                 // holds 3.2*(Ux+b) then zr_t (bf16)

  ux_gemm<<<dim3((T_STEPS*BATCH)/64), dim3(256), 0, stream>>>(x, U, b_real, b_U, uxz);
  scan_k <<<dim3(BATCH/16),           dim3(512), 0, stream>>>(W_real, W_tau, b_tau, uxz);
  y_gemm <<<dim3((T_STEPS*BATCH)/64), dim3(256), 0, stream>>>(uxz, W_out, b_out, (float*)d_out);
}